// Round 10
// baseline (180.627 us; speedup 1.0000x reference)
//
#include <hip/hip_runtime.h>
#include <stdint.h>

typedef _Float16 f16;
typedef f16 f16x8 __attribute__((ext_vector_type(8)));
typedef float f32x4 __attribute__((ext_vector_type(4)));

#define NUM_NODES 20000
#define NUM_EDGES 65536
#define WIDTH 64
#define EDGE_FEAT 6
#define HIDDEN 128
#define BM 256            // edges per workgroup
#define NCHUNK 129        // 128 h-chunks + 1 bias chunk (h==1)
#define KSPLIT 3          // 129 = 3 * 43

#define XH_HALFS (NUM_NODES * WIDTH)   // 1,280,000 halfs for x in f16
#define XCONV_BLKS 625                 // 625 * 2048 halfs = 1,280,000 exactly
#define ZOUT_BLKS 625                  // 625 * 2048 floats = 1,280,000 exactly

// ---------------------------------------------------------------------------
// Prep: (a) build W2g: 129 chunks of [64n x 64k] f16, transposed + XOR-granule
//       swizzled so main-kernel B-fragment ds_read_b128 is conflict-free.
//       physical half index within chunk: n*64 + ((k>>3) ^ (n&7))*8 + (k&7)
//       (b) convert x to f16.  (c) zero d_out (replaces hipMemsetAsync).
// ---------------------------------------------------------------------------
__global__ __launch_bounds__(256) void prep_kernel(
    const float* __restrict__ x, const float* __restrict__ W2,
    const float* __restrict__ b2, f16* __restrict__ ws_h,
    float* __restrict__ out)
{
  __shared__ float row[4096];
  f16* x_h = ws_h;
  f16* W2g = ws_h + XH_HALFS;
  const int blk = blockIdx.x, tid = threadIdx.x;

  if (blk < NCHUNK) {
    const int ki = blk;
    const float* srcrow;
    if (ki < HIDDEN) {
      const float4* src = (const float4*)(W2 + (size_t)ki * 4096);
      #pragma unroll
      for (int i = 0; i < 4; ++i) {
        float4 v = src[tid + 256 * i];
        *(float4*)&row[(tid + 256 * i) * 4] = v;
      }
      __syncthreads();
      srcrow = row;
    } else {
      srcrow = b2;  // bias chunk, read straight from global
    }
    const int obase = tid * 16;
    f16x8 outv0, outv1;
    #pragma unroll
    for (int u = 0; u < 8; ++u) {
      int o = obase + u;
      int n = o >> 6, pg = (o >> 3) & 7, j = o & 7;
      int k = (pg ^ (n & 7)) * 8 + j;
      outv0[u] = (f16)srcrow[k * 64 + n];
    }
    #pragma unroll
    for (int u = 0; u < 8; ++u) {
      int o = obase + 8 + u;
      int n = o >> 6, pg = (o >> 3) & 7, j = o & 7;
      int k = (pg ^ (n & 7)) * 8 + j;
      outv1[u] = (f16)srcrow[k * 64 + n];
    }
    *(f16x8*)&W2g[(size_t)ki * 4096 + obase] = outv0;
    *(f16x8*)&W2g[(size_t)ki * 4096 + obase + 8] = outv1;
  } else if (blk < NCHUNK + XCONV_BLKS) {
    // x fp32 -> f16
    int idx = (blk - NCHUNK) * 2048 + tid * 8;
    if (idx + 8 <= XH_HALFS) {
      float4 a = *(const float4*)(x + idx);
      float4 b = *(const float4*)(x + idx + 4);
      f16x8 hv;
      hv[0] = (f16)a.x; hv[1] = (f16)a.y; hv[2] = (f16)a.z; hv[3] = (f16)a.w;
      hv[4] = (f16)b.x; hv[5] = (f16)b.y; hv[6] = (f16)b.z; hv[7] = (f16)b.w;
      *(f16x8*)&x_h[idx] = hv;
    }
  } else {
    // zero the output buffer
    int idx = (blk - NCHUNK - XCONV_BLKS) * 2048 + tid * 8;
    float4 z = {0.f, 0.f, 0.f, 0.f};
    *(float4*)(out + idx) = z;
    *(float4*)(out + idx + 4) = z;
  }
}

// ---------------------------------------------------------------------------
// Main fused kernel (R10): K-split x3, BK=128 (two 64-K chunks per barrier),
// software-pipelined h-params.
//   blockIdx & 255 -> edge chunk (256 edges); blockIdx >> 8 -> k-third.
// Theory: per-wave iter latency (~4.6k cyc, R9) >> MFMA burst (515 cyc);
// halve barrier/staging events per MFMA (64 MFMAs/barrier) and take the
// W1/b1 load chain off the critical path (params for the NEXT chunk pair
// loaded during the current MFMA section; hv is pure VALU).
// The double loop never touches the bias chunk (ki<=127 there), so hv is
// branch-free; only the odd tail (kk=42) handles ki==128.
// LDS = 32 KB dbuf only -> 3 WGs/CU; regs audited ~163<=170 for 3 waves/SIMD.
// ---------------------------------------------------------------------------
__global__ __launch_bounds__(256, 3) void nnconv_kernel(
    const float* __restrict__ ea, const float* __restrict__ W1,
    const float* __restrict__ b1, const int* __restrict__ senders,
    const int* __restrict__ receivers, const f16* __restrict__ ws_h,
    float* __restrict__ out)
{
  const f16* x_h = ws_h;
  const f16* W2g = ws_h + XH_HALFS;
  __shared__ __align__(16) f16 Bb[2][8192];      // 32 KB: 2 bufs x 2 chunks

  const int tid = threadIdx.x;
  const int lane = tid & 63, wid = tid >> 6;
  const int quad = lane >> 4, l15 = lane & 15;
  const int chunk = blockIdx.x & 255;
  const int kq = blockIdx.x >> 8;                 // 0..2
  const int k0 = kq * 43;                         // 0,43,86
  const int kcount = 43;                          // 3*43 = 129
  const int e0 = chunk * BM;
  const int rowbase = wid * 64;

  // ---- per-lane sender rows + x fragments direct from global (L2-hot)
  int srow[4];
  #pragma unroll
  for (int t = 0; t < 4; ++t)
    srow[t] = senders[e0 + rowbase + t * 16 + l15];

  f16x8 xf[4][2];
  #pragma unroll
  for (int t = 0; t < 4; ++t)
    #pragma unroll
    for (int kc = 0; kc < 2; ++kc)
      xf[t][kc] = *(const f16x8*)(x_h + (size_t)srow[t] * WIDTH + kc * 32 + quad * 8);

  // ---- per-lane edge_attr rows (for h recompute)
  float ear[4][6];
  #pragma unroll
  for (int t = 0; t < 4; ++t) {
    const float* p = ea + (size_t)(e0 + rowbase + t * 16 + l15) * EDGE_FEAT;
    #pragma unroll
    for (int f = 0; f < 6; ++f) ear[t][f] = p[f];
  }

  // ---- per-lane B-fragment LDS offsets (swizzled), within a 4096-half chunk
  int boff[2][4];
  #pragma unroll
  for (int kc = 0; kc < 2; ++kc)
    #pragma unroll
    for (int nt = 0; nt < 4; ++nt) {
      int n = nt * 16 + l15;
      int g = kc * 4 + quad;
      boff[kc][nt] = n * 64 + (g ^ (n & 7)) * 8;
    }

  // ---- prefetch B chunks k0, k0+1
  uint4 pre[4];
  pre[0] = *(const uint4*)(W2g + (size_t)k0 * 4096 + tid * 8);
  pre[1] = *(const uint4*)(W2g + (size_t)k0 * 4096 + 2048 + tid * 8);
  pre[2] = *(const uint4*)(W2g + (size_t)(k0 + 1) * 4096 + tid * 8);
  pre[3] = *(const uint4*)(W2g + (size_t)(k0 + 1) * 4096 + 2048 + tid * 8);

  // ---- pipelined h-MLP params for chunks k0, k0+1 ([slot][0..5]=W1col, [6]=b1)
  float w1r[2][7];
  #pragma unroll
  for (int s = 0; s < 2; ++s) {
    int kw = k0 + s;
    #pragma unroll
    for (int f = 0; f < 6; ++f) w1r[s][f] = W1[f * HIDDEN + kw];
    w1r[s][6] = b1[kw];
  }

  f32x4 acc[4][4];
  #pragma unroll
  for (int t = 0; t < 4; ++t)
    #pragma unroll
    for (int nt = 0; nt < 4; ++nt)
      acc[t][nt] = (f32x4){0.f, 0.f, 0.f, 0.f};

  int kk = 0;
  for (; kk + 2 <= kcount; kk += 2) {
    const int ki = k0 + kk;
    f16* buf = &Bb[(kk >> 1) & 1][0];
    // stage both chunks: identity copy, conflict-free (byte 16*tid per half)
    *(uint4*)&buf[tid * 8]        = pre[0];
    *(uint4*)&buf[2048 + tid * 8] = pre[1];
    *(uint4*)&buf[4096 + tid * 8] = pre[2];
    *(uint4*)&buf[6144 + tid * 8] = pre[3];

    // prefetch next pair (in flight across the barrier, lands during MFMA)
    if (kk + 2 < kcount) {
      pre[0] = *(const uint4*)(W2g + (size_t)(ki + 2) * 4096 + tid * 8);
      pre[1] = *(const uint4*)(W2g + (size_t)(ki + 2) * 4096 + 2048 + tid * 8);
    }
    if (kk + 3 < kcount) {
      pre[2] = *(const uint4*)(W2g + (size_t)(ki + 3) * 4096 + tid * 8);
      pre[3] = *(const uint4*)(W2g + (size_t)(ki + 3) * 4096 + 2048 + tid * 8);
    }

    // hv for both chunks — pure VALU, params already in registers
    f16 hv0[4], hv1[4];
    #pragma unroll
    for (int t = 0; t < 4; ++t) {
      float s0 = w1r[0][6], s1 = w1r[1][6];
      #pragma unroll
      for (int f = 0; f < 6; ++f) {
        s0 = fmaf(ear[t][f], w1r[0][f], s0);
        s1 = fmaf(ear[t][f], w1r[1][f], s1);
      }
      hv0[t] = (f16)fmaxf(s0, 0.f);
      hv1[t] = (f16)fmaxf(s1, 0.f);
    }

    // reload params for the next pair (off critical path; clamp vs OOB at 128)
    if (kk + 2 < kcount) {
      int kw = ki + 2; kw = kw > 127 ? 127 : kw;
      #pragma unroll
      for (int f = 0; f < 6; ++f) w1r[0][f] = W1[f * HIDDEN + kw];
      w1r[0][6] = b1[kw];
    }
    if (kk + 3 < kcount) {
      int kw = ki + 3; kw = kw > 127 ? 127 : kw;
      #pragma unroll
      for (int f = 0; f < 6; ++f) w1r[1][f] = W1[f * HIDDEN + kw];
      w1r[1][6] = b1[kw];
    }

    __syncthreads();  // staging complete

    // ---- chunk ki
    {
      f16x8 bf[2][4];
      #pragma unroll
      for (int kc = 0; kc < 2; ++kc)
        #pragma unroll
        for (int nt = 0; nt < 4; ++nt)
          bf[kc][nt] = *(const f16x8*)&buf[boff[kc][nt]];
      f16x8 sa[4][2];
      #pragma unroll
      for (int t = 0; t < 4; ++t) {
        sa[t][0] = xf[t][0] * hv0[t];
        sa[t][1] = xf[t][1] * hv0[t];
      }
      #pragma unroll
      for (int kc = 0; kc < 2; ++kc)
        #pragma unroll
        for (int t = 0; t < 4; ++t)
          #pragma unroll
          for (int nt = 0; nt < 4; ++nt)
            acc[t][nt] = __builtin_amdgcn_mfma_f32_16x16x32_f16(
                sa[t][kc], bf[kc][nt], acc[t][nt], 0, 0, 0);
    }
    // ---- chunk ki+1 (second 4096-half region of buf)
    {
      f16x8 bf[2][4];
      #pragma unroll
      for (int kc = 0; kc < 2; ++kc)
        #pragma unroll
        for (int nt = 0; nt < 4; ++nt)
          bf[kc][nt] = *(const f16x8*)&buf[4096 + boff[kc][nt]];
      f16x8 sa[4][2];
      #pragma unroll
      for (int t = 0; t < 4; ++t) {
        sa[t][0] = xf[t][0] * hv1[t];
        sa[t][1] = xf[t][1] * hv1[t];
      }
      #pragma unroll
      for (int kc = 0; kc < 2; ++kc)
        #pragma unroll
        for (int t = 0; t < 4; ++t)
          #pragma unroll
          for (int nt = 0; nt < 4; ++nt)
            acc[t][nt] = __builtin_amdgcn_mfma_f32_16x16x32_f16(
                sa[t][kc], bf[kc][nt], acc[t][nt], 0, 0, 0);
    }
  }

  // ---- odd tail (kk == 42): single chunk; ki==128 (bias) iff kq==2
  if (kk < kcount) {
    const int ki = k0 + kk;
    f16* buf = &Bb[(kk >> 1) & 1][0];
    *(uint4*)&buf[tid * 8]        = pre[0];
    *(uint4*)&buf[2048 + tid * 8] = pre[1];

    f16 hv0[4];
    if (ki < HIDDEN) {
      #pragma unroll
      for (int t = 0; t < 4; ++t) {
        float s0 = w1r[0][6];
        #pragma unroll
        for (int f = 0; f < 6; ++f) s0 = fmaf(ear[t][f], w1r[0][f], s0);
        hv0[t] = (f16)fmaxf(s0, 0.f);
      }
    } else {
      #pragma unroll
      for (int t = 0; t < 4; ++t) hv0[t] = (f16)1.f;
    }

    __syncthreads();

    f16x8 bf[2][4];
    #pragma unroll
    for (int kc = 0; kc < 2; ++kc)
      #pragma unroll
      for (int nt = 0; nt < 4; ++nt)
        bf[kc][nt] = *(const f16x8*)&buf[boff[kc][nt]];
    f16x8 sa[4][2];
    #pragma unroll
    for (int t = 0; t < 4; ++t) {
      sa[t][0] = xf[t][0] * hv0[t];
      sa[t][1] = xf[t][1] * hv0[t];
    }
    #pragma unroll
    for (int kc = 0; kc < 2; ++kc)
      #pragma unroll
      for (int t = 0; t < 4; ++t)
        #pragma unroll
        for (int nt = 0; nt < 4; ++nt)
          acc[t][nt] = __builtin_amdgcn_mfma_f32_16x16x32_f16(
              sa[t][kc], bf[kc][nt], acc[t][nt], 0, 0, 0);
  }

  // ---- epilogue: C-layout row = quad*4 + reg, col = l15; scatter-add
  #pragma unroll
  for (int t = 0; t < 4; ++t) {
    int ebase = e0 + rowbase + t * 16 + quad * 4;
    int rc[4];
    #pragma unroll
    for (int r = 0; r < 4; ++r) rc[r] = receivers[ebase + r];
    #pragma unroll
    for (int nt = 0; nt < 4; ++nt) {
      int v = nt * 16 + l15;
      #pragma unroll
      for (int r = 0; r < 4; ++r)
        atomicAdd(out + (size_t)rc[r] * WIDTH + v, acc[t][nt][r]);
    }
  }
}

extern "C" void kernel_launch(void* const* d_in, const int* in_sizes, int n_in,
                              void* d_out, int out_size, void* d_ws, size_t ws_size,
                              hipStream_t stream) {
  const float* x  = (const float*)d_in[0];
  const float* ea = (const float*)d_in[1];
  const float* W1 = (const float*)d_in[2];
  const float* b1 = (const float*)d_in[3];
  const float* W2 = (const float*)d_in[4];
  const float* b2 = (const float*)d_in[5];
  const int* snd  = (const int*)d_in[6];
  const int* rcv  = (const int*)d_in[7];
  float* out = (float*)d_out;
  f16* wsh = (f16*)d_ws;

  prep_kernel<<<NCHUNK + XCONV_BLKS + ZOUT_BLKS, 256, 0, stream>>>(x, W2, b2, wsh, out);
  nnconv_kernel<<<KSPLIT * (NUM_EDGES / BM), 256, 0, stream>>>(ea, W1, b1, snd, rcv, wsh, out);
}